// Round 2
// baseline (199.400 us; speedup 1.0000x reference)
//
#include <hip/hip_runtime.h>
#include <stdint.h>

// Problem constants (from reference setup_inputs): B=2, L=2048, N=4, D=2048
#define NC    8192      // N*D, per-row h length
#define D_    2048
#define NOUTS 24        // N*N + 2N
#define WPAD  8224      // padded row stride (floats) for transposed w: 8192 + 32

// ---------------- prep: wp[o][c] = w[c][o]  (fp32, padded rows) ----------------
__global__ void prep_w_kernel(const float* __restrict__ w, float* __restrict__ wp) {
    int idx = blockIdx.x * blockDim.x + threadIdx.x;
    if (idx >= NOUTS * NC) return;
    int o = idx / NC;          // consecutive idx -> consecutive c: coalesced writes
    int c = idx - o * NC;
    wp[o * WPAD + c] = w[c * NOUTS + o];
}

// ---------------- fused main kernel: one wave per (b,l) row ----------------
// Phase 1: stream h row (fp32, coalesced float4), accumulate 24-wide GEMV with
//          gamma-scaled h against transposed w, plus sum(h^2). Wave butterfly
//          reduce. Phase S: sigmoids + exp + 10-iter 4x4 Sinkhorn, all lanes
//          redundant in registers. Phase 2: re-read h (L2/L3-hot), emit
//          out[m,d] = Hpost[m]*h_pre[d] + sum_n P[m,n]*h[n,d] as FP32
//          (round-1 post-mortem: d_out is float*, not bf16).
__global__ __launch_bounds__(256, 4) void fused_kernel(
    const float* __restrict__ h, const float* __restrict__ gamma,
    const float* __restrict__ wp, const float* __restrict__ alpha,
    const float* __restrict__ beta, const int* __restrict__ it_ptr,
    float* __restrict__ out, int nrows)
{
    const int wave = threadIdx.x >> 6;
    const int lane = threadIdx.x & 63;
    const int row  = (blockIdx.x << 2) | wave;
    if (row >= nrows) return;
    const float* hrow = h + (size_t)row * NC;

    // ---- phase 1: GEMV + sumsq ----
    float acc[NOUTS];
#pragma unroll
    for (int o = 0; o < NOUTS; ++o) acc[o] = 0.0f;
    float sumsq = 0.0f;

    const int base = lane << 2;   // 4*lane
#pragma unroll 2
    for (int j = 0; j < 32; ++j) {
        const int c0 = base + (j << 8);
        const float4 h4 = *reinterpret_cast<const float4*>(hrow + c0);
        const float4 g4 = *reinterpret_cast<const float4*>(gamma + c0);
        sumsq += h4.x * h4.x + h4.y * h4.y + h4.z * h4.z + h4.w * h4.w;
        const float v0 = h4.x * g4.x, v1 = h4.y * g4.y;
        const float v2 = h4.z * g4.z, v3 = h4.w * g4.w;
#pragma unroll
        for (int o = 0; o < NOUTS; ++o) {
            const float4 w4 = *reinterpret_cast<const float4*>(wp + o * WPAD + c0);
            acc[o] += v0 * w4.x + v1 * w4.y + v2 * w4.z + v3 * w4.w;
        }
    }

    // ---- wave butterfly reduction (64 lanes), all lanes end with full sums ----
#pragma unroll
    for (int m = 1; m < 64; m <<= 1) {
        sumsq += __shfl_xor(sumsq, m, 64);
#pragma unroll
        for (int o = 0; o < NOUTS; ++o) acc[o] += __shfl_xor(acc[o], m, 64);
    }

    // ---- tiny per-row math (redundant across lanes, registers only) ----
    const float r_ = sqrtf((float)NC / sumsq);   // 1/r, r = ||h||/sqrt(nc)
    const float a0 = alpha[0], a1 = alpha[1], a2 = alpha[2];

    float Hpre[4], Hpost[4], M[16];
#pragma unroll
    for (int n = 0; n < 4; ++n) {
        const float x = r_ * acc[n] * a0 + beta[n];
        Hpre[n] = __builtin_amdgcn_rcpf(1.0f + __expf(-x));
        const float y = r_ * acc[4 + n] * a1 + beta[4 + n];
        Hpost[n] = 2.0f * __builtin_amdgcn_rcpf(1.0f + __expf(-y));
    }
#pragma unroll
    for (int k = 0; k < 16; ++k)
        M[k] = __expf(r_ * acc[8 + k] * a2 + beta[8 + k]);

    float u[4] = {1.f, 1.f, 1.f, 1.f}, v[4] = {1.f, 1.f, 1.f, 1.f};
    // Robust read of the iteration-count scalar: if it arrives float-encoded,
    // the int view is a huge number -> reinterpret. Extra converged Sinkhorn
    // iterations are numerically harmless; runaway loops are not.
    int iters = *it_ptr;
    if (iters < 0 || iters > 10000) {
        const float f = __int_as_float(iters);
        iters = (f >= 0.0f && f < 10000.0f) ? (int)f : 10;
    }
    for (int it = 0; it < iters; ++it) {
#pragma unroll
        for (int i = 0; i < 4; ++i)
            u[i] = __builtin_amdgcn_rcpf(
                M[4*i+0] * v[0] + M[4*i+1] * v[1] + M[4*i+2] * v[2] + M[4*i+3] * v[3] + 1e-8f);
#pragma unroll
        for (int j2 = 0; j2 < 4; ++j2)
            v[j2] = __builtin_amdgcn_rcpf(
                M[j2] * u[0] + M[4+j2] * u[1] + M[8+j2] * u[2] + M[12+j2] * u[3] + 1e-8f);
    }
    float P[16];
#pragma unroll
    for (int i = 0; i < 4; ++i)
#pragma unroll
        for (int j2 = 0; j2 < 4; ++j2)
            P[4*i + j2] = u[i] * M[4*i + j2] * v[j2];

    // ---- phase 2: outputs (re-read h, hot in L2/L3), fp32 float4 stores ----
    float* orow = out + (size_t)row * NC;
#pragma unroll 2
    for (int t = 0; t < 8; ++t) {
        const int d0 = base + (t << 8);
        float hn[4][4];
#pragma unroll
        for (int n = 0; n < 4; ++n) {
            const float4 x4 = *reinterpret_cast<const float4*>(hrow + n * D_ + d0);
            hn[n][0] = x4.x; hn[n][1] = x4.y; hn[n][2] = x4.z; hn[n][3] = x4.w;
        }
        float hp[4];
#pragma unroll
        for (int k = 0; k < 4; ++k)
            hp[k] = Hpre[0]*hn[0][k] + Hpre[1]*hn[1][k] + Hpre[2]*hn[2][k] + Hpre[3]*hn[3][k];
#pragma unroll
        for (int m = 0; m < 4; ++m) {
            float4 o4;
            o4.x = Hpost[m]*hp[0] + P[4*m+0]*hn[0][0] + P[4*m+1]*hn[1][0] + P[4*m+2]*hn[2][0] + P[4*m+3]*hn[3][0];
            o4.y = Hpost[m]*hp[1] + P[4*m+0]*hn[0][1] + P[4*m+1]*hn[1][1] + P[4*m+2]*hn[2][1] + P[4*m+3]*hn[3][1];
            o4.z = Hpost[m]*hp[2] + P[4*m+0]*hn[0][2] + P[4*m+1]*hn[1][2] + P[4*m+2]*hn[2][2] + P[4*m+3]*hn[3][2];
            o4.w = Hpost[m]*hp[3] + P[4*m+0]*hn[0][3] + P[4*m+1]*hn[1][3] + P[4*m+2]*hn[2][3] + P[4*m+3]*hn[3][3];
            *reinterpret_cast<float4*>(orow + m * D_ + d0) = o4;
        }
    }
}

extern "C" void kernel_launch(void* const* d_in, const int* in_sizes, int n_in,
                              void* d_out, int out_size, void* d_ws, size_t ws_size,
                              hipStream_t stream) {
    const float* h     = (const float*)d_in[0];   // [B,L,N,D] fp32
    const float* gamma = (const float*)d_in[1];   // [8192] fp32
    const float* w     = (const float*)d_in[2];   // [8192,24] fp32
    const float* alpha = (const float*)d_in[3];   // [3] fp32
    const float* beta  = (const float*)d_in[4];   // [24] fp32
    const int*   itp   = (const int*)d_in[5];     // scalar (10)
    float*       out   = (float*)d_out;           // fp32 output (round-1 post-mortem)

    const int nrows = in_sizes[0] / NC;           // 4096
    float* wp = (float*)d_ws;                     // needs 24*8224*4 = 789,504 B

    prep_w_kernel<<<(NOUTS * NC + 255) / 256, 256, 0, stream>>>(w, wp);
    fused_kernel<<<(nrows + 3) / 4, 256, 0, stream>>>(h, gamma, wp, alpha, beta, itp, out, nrows);
}